// Round 5
// baseline (2260.922 us; speedup 1.0000x reference)
//
#include <hip/hip_runtime.h>
#include <math.h>

// Problem constants
#define BB 128
#define SS 64
#define EE 300
#define HH 512
#define LL 5
#define BSH (BB*SS*HH)   // 4,194,304
#define KP  320          // E padded to multiple of 32 for bf16 MFMA
#define NGRP 8           // independent chain-groups (16 chains each)
#define BPG  24          // blocks per group (8 N-tiles x 3 gates)
#define GRID_FUSED (NGRP*BPG)   // 192
#define WS_ROW 520               // LDS weight row stride (elems): 2-way bank rotate
#define WS_PLANE (64*WS_ROW)     // one bf16 plane: 64 N-rows x 520
#define LDS_DYN_BYTES (2*WS_PLANE*2)  // 133,120 B (hi+lo planes)

typedef __attribute__((ext_vector_type(8))) short bf16x8;        // 8 bf16 = 4 VGPRs
typedef __attribute__((ext_vector_type(4))) float f32x4;
typedef __attribute__((ext_vector_type(4))) unsigned int u32x4;  // 16B staging

__device__ __forceinline__ float fast_sigmoid(float x) {
    return 1.0f / (1.0f + __expf(-x));
}
__device__ __forceinline__ float fast_tanh(float x) {
    x = fminf(fmaxf(x, -20.0f), 20.0f);
    float e = __expf(2.0f * x);
    return (e - 1.0f) / (e + 1.0f);
}
// fp32 -> bf16 round-to-nearest-even (bit trick; inputs finite here)
__device__ __forceinline__ unsigned short f2bf(float f) {
    unsigned int u = __float_as_uint(f);
    u += 0x7fffu + ((u >> 16) & 1u);
    return (unsigned short)(u >> 16);
}
__device__ __forceinline__ float bf2f(unsigned short h) {
    return __uint_as_float((unsigned int)h << 16);
}
// Split fp32 into hi/lo bf16 pair: v ~= hi + lo, residual ~2^-18 * |v|
__device__ __forceinline__ void split2(float v, unsigned short& hi, unsigned short& lo) {
    hi = f2bf(v);
    lo = f2bf(v - bf2f(hi));
}

// ---------------------------------------------------------------------------
// Prep: (a) split 6 weight matrices into bf16 hi/lo planes (Wx padded K->320),
// (b) per-(b,t) compact active-children lists, (c) zero the barrier counters.
// ---------------------------------------------------------------------------
__global__ __launch_bounds__(256) void prep_kernel(
    const int* __restrict__ bfs, const int* __restrict__ children,
    const float* __restrict__ Wix, const float* __restrict__ Wfx, const float* __restrict__ Wux,
    const float* __restrict__ Wih, const float* __restrict__ Wfh, const float* __restrict__ Wuh,
    unsigned short* __restrict__ Wixh, unsigned short* __restrict__ Wixl,
    unsigned short* __restrict__ Wfxh, unsigned short* __restrict__ Wfxl,
    unsigned short* __restrict__ Wuxh, unsigned short* __restrict__ Wuxl,
    unsigned short* __restrict__ Wihh, unsigned short* __restrict__ Wihl,
    unsigned short* __restrict__ Wfhh, unsigned short* __restrict__ Wfhl,
    unsigned short* __restrict__ Wuhh, unsigned short* __restrict__ Wuhl,
    unsigned char* __restrict__ clist, int* __restrict__ ccnt, int* __restrict__ bars)
{
    const int gid = blockIdx.x * 256 + threadIdx.x;
    const int G = gridDim.x * 256;
    for (int i = gid; i < NGRP * 256; i += G) bars[i] = 0;
    for (int i = gid; i < 3 * HH * KP; i += G) {
        int g = i / (HH * KP), rem = i % (HH * KP), r = rem / KP, k = rem % KP;
        const float* src = (g == 0) ? Wix : (g == 1) ? Wfx : Wux;
        unsigned short* dh = (g == 0) ? Wixh : (g == 1) ? Wfxh : Wuxh;
        unsigned short* dl = (g == 0) ? Wixl : (g == 1) ? Wfxl : Wuxl;
        float v = (k < EE) ? src[(size_t)r * EE + k] : 0.0f;
        unsigned short hi, lo; split2(v, hi, lo);
        dh[r * KP + k] = hi; dl[r * KP + k] = lo;
    }
    for (int i = gid; i < 3 * HH * HH; i += G) {
        int g = i / (HH * HH), idx = i % (HH * HH);
        const float* src = (g == 0) ? Wih : (g == 1) ? Wfh : Wuh;
        unsigned short* dh = (g == 0) ? Wihh : (g == 1) ? Wfhh : Wuhh;
        unsigned short* dl = (g == 0) ? Wihl : (g == 1) ? Wfhl : Wuhl;
        unsigned short hi, lo; split2(src[idx], hi, lo);
        dh[idx] = hi; dl[idx] = lo;
    }
    if (gid < BB * SS) {
        const int b = gid >> 6, t = gid & 63;
        unsigned long long w = 0;
        for (int tp = 0; tp < t; ++tp) w |= 1ull << (bfs[b * SS + tp] & 63);
        const int cur = bfs[b * SS + t];
        const int* crow = children + (size_t)(b * SS + cur) * SS;
        unsigned char* lst = clist + (size_t)gid * SS;
        int cnt = 0;
        for (int s = 0; s < SS; ++s)
            if (crow[s] != 0 && ((w >> s) & 1ull)) lst[cnt++] = (unsigned char)s;
        ccnt[gid] = cnt;
    }
}

// ---------------------------------------------------------------------------
// XP precompute, split-bf16 MFMA. [8192 x 320pad] @ [320 x 512] per gate.
// Tile 32M x 64N, grid (256, 3). A staged once in LDS (hi/lo, full K);
// B fragments loaded directly from global (L2-resident). 2 barriers/block.
// D = Ah*Bh + Ah*Bl + Al*Bh  (lo*lo dropped, rel ~2^-18).
// ---------------------------------------------------------------------------
__global__ __launch_bounds__(256) void xp_mfma(
    const int* __restrict__ x, const float* __restrict__ embed,
    const unsigned short* __restrict__ Wixh, const unsigned short* __restrict__ Wixl,
    const unsigned short* __restrict__ Wfxh, const unsigned short* __restrict__ Wfxl,
    const unsigned short* __restrict__ Wuxh, const unsigned short* __restrict__ Wuxl,
    const float* __restrict__ bix, const float* __restrict__ bih,
    const float* __restrict__ bfx, const float* __restrict__ bfh,
    const float* __restrict__ bux, const float* __restrict__ buh,
    float* __restrict__ XPi, float* __restrict__ XPf, float* __restrict__ XPu)
{
    const int mb = blockIdx.x;            // 256 tiles of 32 rows of B*S
    const int g  = blockIdx.y;            // gate
    const unsigned short* __restrict__ Wbh = (g == 0) ? Wixh : (g == 1) ? Wfxh : Wuxh;
    const unsigned short* __restrict__ Wbl = (g == 0) ? Wixl : (g == 1) ? Wfxl : Wuxl;
    const float* __restrict__ b1 = (g == 0) ? bix : (g == 1) ? bfx : bux;
    const float* __restrict__ b2 = (g == 0) ? bih : (g == 1) ? bfh : buh;
    float* __restrict__ OUT = (g == 0) ? XPi : (g == 1) ? XPf : XPu;

    const int row0 = mb * 32;
    __shared__ unsigned short As[2][32 * 328];   // hi/lo planes, full K, pad 328
    __shared__ int toks[32];

    const int tid = threadIdx.x;
    if (tid < 32) toks[tid] = x[row0 + tid];
    __syncthreads();

    for (int i = tid; i < 32 * 75; i += 256) {
        int r = i / 75, c = i - r * 75;
        const float4 v = *(const float4*)(embed + (size_t)toks[r] * EE + c * 4);
        ushort4 hv, lv;
        split2(v.x, hv.x, lv.x); split2(v.y, hv.y, lv.y);
        split2(v.z, hv.z, lv.z); split2(v.w, hv.w, lv.w);
        *(ushort4*)&As[0][r * 328 + c * 4] = hv;
        *(ushort4*)&As[1][r * 328 + c * 4] = lv;
    }
    for (int i = tid; i < 32 * 20; i += 256) {
        int r = i / 20, k = EE + (i - r * 20);
        As[0][r * 328 + k] = 0; As[1][r * 328 + k] = 0;
    }
    __syncthreads();

    const int lane = tid & 63, wave = tid >> 6;
    const int quad = lane >> 4, col = lane & 15;
    const int wn = wave * 16;             // each wave: 16-wide N-slice, full 32 M

    for (int nt = 0; nt < 8; ++nt) {
        const int gn = nt * 64 + wn + col;        // global output column (B row)
        const size_t wrow = (size_t)gn * KP;
        f32x4 acc0 = {0.f, 0.f, 0.f, 0.f}, acc1 = {0.f, 0.f, 0.f, 0.f};
        #pragma unroll
        for (int kq = 0; kq < 10; ++kq) {         // K = 320 = 10 * 32
            const int ka = kq * 32 + quad * 8;
            bf16x8 bh  = *(const bf16x8*)(Wbh + wrow + ka);   // direct L2 load
            bf16x8 bl  = *(const bf16x8*)(Wbl + wrow + ka);
            bf16x8 a0h = *(const bf16x8*)&As[0][col * 328 + ka];
            bf16x8 a0l = *(const bf16x8*)&As[1][col * 328 + ka];
            bf16x8 a1h = *(const bf16x8*)&As[0][(16 + col) * 328 + ka];
            bf16x8 a1l = *(const bf16x8*)&As[1][(16 + col) * 328 + ka];
            acc0 = __builtin_amdgcn_mfma_f32_16x16x32_bf16(a0h, bh, acc0, 0, 0, 0);
            acc1 = __builtin_amdgcn_mfma_f32_16x16x32_bf16(a1h, bh, acc1, 0, 0, 0);
            acc0 = __builtin_amdgcn_mfma_f32_16x16x32_bf16(a0h, bl, acc0, 0, 0, 0);
            acc1 = __builtin_amdgcn_mfma_f32_16x16x32_bf16(a1h, bl, acc1, 0, 0, 0);
            acc0 = __builtin_amdgcn_mfma_f32_16x16x32_bf16(a0l, bh, acc0, 0, 0, 0);
            acc1 = __builtin_amdgcn_mfma_f32_16x16x32_bf16(a1l, bh, acc1, 0, 0, 0);
        }
        const float bb = b1[gn] + b2[gn];
        #pragma unroll
        for (int reg = 0; reg < 4; ++reg) {
            const int ml = quad * 4 + reg;
            OUT[(size_t)(row0 + ml) * HH + gn]      = acc0[reg] + bb;
            OUT[(size_t)(row0 + 16 + ml) * HH + gn] = acc1[reg] + bb;
        }
    }
}

// ---------------------------------------------------------------------------
// Group barrier (known-correct from r4): single-use counter per (group, step,
// phase), zeroed by prep. Agent-scope fences for cross-XCD visibility.
// ---------------------------------------------------------------------------
__device__ __forceinline__ void group_barrier(int* cnt) {
    __syncthreads();
    if (threadIdx.x == 0) {
        __threadfence();   // release (L2 wb across XCDs)
        __hip_atomic_fetch_add(cnt, 1, __ATOMIC_RELAXED, __HIP_MEMORY_SCOPE_AGENT);
        while (__hip_atomic_load(cnt, __ATOMIC_RELAXED, __HIP_MEMORY_SCOPE_AGENT) < BPG)
            __builtin_amdgcn_s_sleep(2);
        __threadfence();   // acquire (invalidate stale lines)
    }
    __syncthreads();
}

// ---------------------------------------------------------------------------
// Fused recurrence v2: one cooperative launch, 192 blocks = 8 groups x 24.
// Group g owns chains [16g,16g+16).
//  - Weights LDS-RESIDENT (dynamic 130 KB/block, 1 block/CU): each block holds
//    its 64-N-row hi/lo slice for all 63 steps -> immune to the barrier L2
//    invalidate, zero per-step weight traffic.
//  - Gates spread over ALL 24 blocks: one thread per (chain,h) task
//    (8192 tasks / 6144 threads, blocks 0..7 take a 2nd task).
//  - XP rows for step t+1 prefetched into REGISTERS before the fences.
// ---------------------------------------------------------------------------
__global__ __launch_bounds__(256, 1) void fused_steps(
    const int* __restrict__ bfs, const unsigned char* __restrict__ clist,
    const int* __restrict__ ccnt,
    const float* __restrict__ XPi, const float* __restrict__ XPf, const float* __restrict__ XPu,
    const unsigned short* __restrict__ Wihh, const unsigned short* __restrict__ Wihl,
    const unsigned short* __restrict__ Wfhh, const unsigned short* __restrict__ Wfhl,
    const unsigned short* __restrict__ Wuhh, const unsigned short* __restrict__ Wuhl,
    float* __restrict__ HWi, float* __restrict__ HWf, float* __restrict__ HWu,
    float* __restrict__ C, float* __restrict__ hf32,
    unsigned short* __restrict__ h_hi, unsigned short* __restrict__ h_lo,
    int* __restrict__ bars)
{
    extern __shared__ unsigned short Ws[];      // [2][64*520] weight hi/lo slice
    __shared__ int s_cur_all[16 * 64];          // bfs row per (chain, t)
    __shared__ int s_ccnt[16 * 64];             // child count per (chain, t)

    const int g = blockIdx.x & 7;               // group
    const int l = blockIdx.x >> 3;              // 0..23 within group
    const int tid = threadIdx.x;
    const int m0 = g * 16;                      // first chain of this group

    // proj tile: gate = l>>3, n0 = (l&7)*64
    const int gate = l >> 3;
    const int n0 = (l & 7) * 64;
    const unsigned short* __restrict__ Wbh = (gate == 0) ? Wihh : (gate == 1) ? Wfhh : Wuhh;
    const unsigned short* __restrict__ Wbl = (gate == 0) ? Wihl : (gate == 1) ? Wfhl : Wuhl;
    float* __restrict__ OUT = (gate == 0) ? HWi : (gate == 1) ? HWf : HWu;

    const int lane = tid & 63, wave = tid >> 6;
    const int quad = lane >> 4, col = lane & 15;
    const int wn = wave * 16;                   // wave's 16-wide N-slice

    // ---- one-time init: weights -> LDS, bfs/ccnt -> LDS ----
    for (int i = tid; i < 2 * 64 * 64; i += 256) {      // 16B chunks
        const int plane = i >> 12, j = i & 4095, r = j >> 6, c = j & 63;
        const unsigned short* src = plane ? Wbl : Wbh;
        *(u32x4*)&Ws[plane * WS_PLANE + r * WS_ROW + c * 8] =
            *(const u32x4*)(src + (size_t)(n0 + r) * HH + c * 8);
    }
    for (int i = tid; i < 16 * 64; i += 256) {
        s_cur_all[i] = bfs[(m0 + (i >> 6)) * SS + (i & 63)];
        s_ccnt[i]    = ccnt[(m0 + (i >> 6)) * SS + (i & 63)];
    }
    __syncthreads();

    // gates task mapping: task = l*256+tid (+6144); chain = task>>9, h = task&511
    const int gtid = l * 256 + tid;
    const int nrep = (gtid < 8192 - 6144) ? 2 : 1;
    int chain_[2], h_[2];
    chain_[0] = gtid >> 9;            h_[0] = gtid & 511;
    chain_[1] = (gtid + 6144) >> 9;   h_[1] = (gtid + 6144) & 511;

    // XP registers for current step (preload t=0)
    float xpi_c[2], xpf_c[2], xpu_c[2], xpi_n[2], xpf_n[2], xpu_n[2];
    #pragma unroll
    for (int rep = 0; rep < 2; ++rep) {
        if (rep < nrep) {
            const int cur = s_cur_all[(chain_[rep] << 6) + 0];
            const size_t xb = ((size_t)(m0 + chain_[rep]) * SS + cur) * HH + h_[rep];
            xpi_c[rep] = XPi[xb]; xpf_c[rep] = XPf[xb]; xpu_c[rep] = XPu[xb];
        }
    }

    int* gbars = bars + g * 256;

    for (int t = 0; t < SS; ++t) {
        // ================= gates phase (all blocks, 1-2 tasks/thread) ========
        #pragma unroll
        for (int rep = 0; rep < 2; ++rep) {
            if (rep >= nrep) continue;
            const int chain = chain_[rep], h = h_[rep];
            const int cur = s_cur_all[(chain << 6) + t];
            const int cnt = s_ccnt[(chain << 6) + t];
            const size_t crow = (size_t)(m0 + chain) * SS;
            const unsigned char* cl = clist + (crow + t) * SS;
            const float xpi = xpi_c[rep], xpf = xpf_c[rep], xpu = xpu_c[rep];

            float ai = 0.f, af = 0.f, au = 0.f, fc = 0.f;
            for (int idx = 0; idx < cnt; ++idx) {
                const size_t cb = (crow + cl[idx]) * HH + h;
                const float pi = HWi[cb];
                const float pf = HWf[cb];
                const float pu = HWu[cb];
                const float cc = C[cb];
                ai += pi; af += pf; au += pu;
                fc += fast_sigmoid(pf + xpf) * cc;   // per-child forget * C
            }

            const float ig = fast_sigmoid(xpi + ai);
            const float og = fast_sigmoid(xpf + af);   // o shares fx/fh per source
            const float ug = fast_tanh(xpu + au);
            const float c  = ig * ug + fc;
            const float hv = og * fast_tanh(c);

            C[(crow + cur) * HH + h] = c;
            unsigned short hh, hl;
            split2(hv, hh, hl);
            h_hi[(size_t)(m0 + chain) * HH + h] = hh;
            h_lo[(size_t)(m0 + chain) * HH + h] = hl;
            if (t == SS - 1) hf32[(size_t)(m0 + chain) * HH + h] = hv;
        }
        if (t == SS - 1) break;

        // prefetch XP(t+1) into registers (issued before the fences; the
        // barrier's vmcnt drain completes them "for free")
        #pragma unroll
        for (int rep = 0; rep < 2; ++rep) {
            if (rep < nrep) {
                const int cur = s_cur_all[(chain_[rep] << 6) + t + 1];
                const size_t xb = ((size_t)(m0 + chain_[rep]) * SS + cur) * HH + h_[rep];
                xpi_n[rep] = XPi[xb]; xpf_n[rep] = XPf[xb]; xpu_n[rep] = XPu[xb];
            }
        }

        group_barrier(gbars + t * 2);

        // ================= proj phase (all 24 blocks) =================
        // A (h hi/lo) direct from global; B (weights) from LDS.
        f32x4 accA = {0.f, 0.f, 0.f, 0.f}, accB = {0.f, 0.f, 0.f, 0.f};
        const size_t hrow = (size_t)(m0 + col) * HH;
        #pragma unroll
        for (int kq = 0; kq < 16; ++kq) {          // K = 512 = 16 * 32
            const int ka = kq * 32 + quad * 8;
            bf16x8 ah = *(const bf16x8*)(h_hi + hrow + ka);
            bf16x8 al = *(const bf16x8*)(h_lo + hrow + ka);
            bf16x8 bh = *(const bf16x8*)&Ws[(wn + col) * WS_ROW + ka];
            bf16x8 bl = *(const bf16x8*)&Ws[WS_PLANE + (wn + col) * WS_ROW + ka];
            accA = __builtin_amdgcn_mfma_f32_16x16x32_bf16(ah, bh, accA, 0, 0, 0);
            accB = __builtin_amdgcn_mfma_f32_16x16x32_bf16(ah, bl, accB, 0, 0, 0);
            accA = __builtin_amdgcn_mfma_f32_16x16x32_bf16(al, bh, accA, 0, 0, 0);
        }
        const f32x4 acc = accA + accB;

        // scatter: C/D layout col=N, quad*4+reg=M
        #pragma unroll
        for (int reg = 0; reg < 4; ++reg) {
            const int m = quad * 4 + reg;
            const int cur = s_cur_all[(m << 6) + t];
            OUT[((size_t)(m0 + m) * SS + cur) * HH + n0 + wn + col] = acc[reg];
        }
        group_barrier(gbars + t * 2 + 1);

        #pragma unroll
        for (int rep = 0; rep < 2; ++rep) {
            xpi_c[rep] = xpi_n[rep]; xpf_c[rep] = xpf_n[rep]; xpu_c[rep] = xpu_n[rep];
        }
    }
}

// ---------------------------------------------------------------------------
// Final projection: out[b,l] = hcur[b,:] . Wout[l,:] + bout[l]  (fp32)
// ---------------------------------------------------------------------------
__global__ __launch_bounds__(64) void out_kernel(
    const float* __restrict__ hcur,
    const float* __restrict__ Wout, const float* __restrict__ bout,
    float* __restrict__ out)
{
    const int b = blockIdx.x;
    const int lane = threadIdx.x;
    float acc[LL];
    #pragma unroll
    for (int l = 0; l < LL; ++l) acc[l] = 0.0f;
    for (int h = lane; h < HH; h += 64) {
        const float hv = hcur[(size_t)b * HH + h];
        #pragma unroll
        for (int l = 0; l < LL; ++l) acc[l] += hv * Wout[l * HH + h];
    }
    #pragma unroll
    for (int off = 32; off > 0; off >>= 1) {
        #pragma unroll
        for (int l = 0; l < LL; ++l) acc[l] += __shfl_down(acc[l], off);
    }
    if (lane == 0) {
        #pragma unroll
        for (int l = 0; l < LL; ++l) out[b * LL + l] = acc[l] + bout[l];
    }
}

extern "C" void kernel_launch(void* const* d_in, const int* in_sizes, int n_in,
                              void* d_out, int out_size, void* d_ws, size_t ws_size,
                              hipStream_t stream)
{
    (void)in_sizes; (void)n_in; (void)out_size; (void)ws_size;
    const int*   x        = (const int*)d_in[0];
    const int*   bfs      = (const int*)d_in[1];
    const int*   children = (const int*)d_in[2];
    const float* embed    = (const float*)d_in[3];
    const float* Wix = (const float*)d_in[4];
    const float* bix = (const float*)d_in[5];
    const float* Wih = (const float*)d_in[6];
    const float* bih = (const float*)d_in[7];
    const float* Wfx = (const float*)d_in[8];
    const float* bfx = (const float*)d_in[9];
    const float* Wfh = (const float*)d_in[10];
    const float* bfh = (const float*)d_in[11];
    const float* Wux = (const float*)d_in[12];
    const float* bux = (const float*)d_in[13];
    const float* Wuh = (const float*)d_in[14];
    const float* buh = (const float*)d_in[15];
    const float* Wout = (const float*)d_in[16];
    const float* bout = (const float*)d_in[17];
    float* out = (float*)d_out;

    // Workspace layout (~124 MB; every chunk size is a multiple of 256 B)
    char* p = (char*)d_ws;
    float* XPi = (float*)p;            p += (size_t)BSH * 4;
    float* XPf = (float*)p;            p += (size_t)BSH * 4;
    float* XPu = (float*)p;            p += (size_t)BSH * 4;
    float* Cst = (float*)p;            p += (size_t)BSH * 4;
    float* HWi = (float*)p;            p += (size_t)BSH * 4;
    float* HWf = (float*)p;            p += (size_t)BSH * 4;
    float* HWu = (float*)p;            p += (size_t)BSH * 4;
    float* hf32 = (float*)p;           p += (size_t)BB * HH * 4;
    unsigned short* h_hi = (unsigned short*)p; p += (size_t)BB * HH * 2;
    unsigned short* h_lo = (unsigned short*)p; p += (size_t)BB * HH * 2;
    unsigned short* Wixh = (unsigned short*)p; p += (size_t)HH * KP * 2;
    unsigned short* Wixl = (unsigned short*)p; p += (size_t)HH * KP * 2;
    unsigned short* Wfxh = (unsigned short*)p; p += (size_t)HH * KP * 2;
    unsigned short* Wfxl = (unsigned short*)p; p += (size_t)HH * KP * 2;
    unsigned short* Wuxh = (unsigned short*)p; p += (size_t)HH * KP * 2;
    unsigned short* Wuxl = (unsigned short*)p; p += (size_t)HH * KP * 2;
    unsigned short* Wihh = (unsigned short*)p; p += (size_t)HH * HH * 2;
    unsigned short* Wihl = (unsigned short*)p; p += (size_t)HH * HH * 2;
    unsigned short* Wfhh = (unsigned short*)p; p += (size_t)HH * HH * 2;
    unsigned short* Wfhl = (unsigned short*)p; p += (size_t)HH * HH * 2;
    unsigned short* Wuhh = (unsigned short*)p; p += (size_t)HH * HH * 2;
    unsigned short* Wuhl = (unsigned short*)p; p += (size_t)HH * HH * 2;
    unsigned char* clist = (unsigned char*)p;  p += (size_t)BB * SS * SS;
    int* ccnt = (int*)p;               p += (size_t)BB * SS * 4;
    int* bars = (int*)p;               p += (size_t)NGRP * 256 * 4;

    // Allow >64KB dynamic LDS (idempotent; ignore result if unsupported)
    (void)hipFuncSetAttribute((const void*)fused_steps,
                              hipFuncAttributeMaxDynamicSharedMemorySize,
                              LDS_DYN_BYTES);

    prep_kernel<<<dim3(256), 256, 0, stream>>>(
        bfs, children, Wix, Wfx, Wux, Wih, Wfh, Wuh,
        Wixh, Wixl, Wfxh, Wfxl, Wuxh, Wuxl,
        Wihh, Wihl, Wfhh, Wfhl, Wuhh, Wuhl, clist, ccnt, bars);

    xp_mfma<<<dim3(256, 3), 256, 0, stream>>>(
        x, embed, Wixh, Wixl, Wfxh, Wfxl, Wuxh, Wuxl,
        bix, bih, bfx, bfh, bux, buh, XPi, XPf, XPu);

    {
        void* args[] = {
            (void*)&bfs, (void*)&clist, (void*)&ccnt,
            (void*)&XPi, (void*)&XPf, (void*)&XPu,
            (void*)&Wihh, (void*)&Wihl, (void*)&Wfhh, (void*)&Wfhl,
            (void*)&Wuhh, (void*)&Wuhl,
            (void*)&HWi, (void*)&HWf, (void*)&HWu,
            (void*)&Cst, (void*)&hf32, (void*)&h_hi, (void*)&h_lo,
            (void*)&bars
        };
        hipLaunchCooperativeKernel((void*)fused_steps, dim3(GRID_FUSED), dim3(256),
                                   args, LDS_DYN_BYTES, stream);
    }

    out_kernel<<<dim3(BB), 64, 0, stream>>>(hf32, Wout, bout, out);
}

// Round 6
// 1083.010 us; speedup vs baseline: 2.0876x; 2.0876x over previous
//
#include <hip/hip_runtime.h>
#include <math.h>

// Problem constants
#define BB 128
#define SS 64
#define EE 300
#define HH 512
#define LL 5
#define BSH (BB*SS*HH)   // 4,194,304
#define KP  320          // E padded to multiple of 32 for bf16 MFMA
#define NGRP 8           // chain-groups (16 chains each)
#define BPG  32          // blocks per group (h-slices of 16)
#define HSL  16          // h columns per block
#define WSROW 520        // LDS weight row stride (elems) -> 4-bank rotate
#define WS_BYTES (2*3*16*WSROW*2)   // 99,840 B dynamic LDS

typedef __attribute__((ext_vector_type(8))) short bf16x8;
typedef __attribute__((ext_vector_type(4))) float f32x4;
typedef __attribute__((ext_vector_type(4))) unsigned int u32x4;

__device__ __forceinline__ float fast_sigmoid(float x) {
    return 1.0f / (1.0f + __expf(-x));
}
__device__ __forceinline__ float fast_tanh(float x) {
    x = fminf(fmaxf(x, -20.0f), 20.0f);
    float e = __expf(2.0f * x);
    return (e - 1.0f) / (e + 1.0f);
}
__device__ __forceinline__ unsigned short f2bf(float f) {
    unsigned int u = __float_as_uint(f);
    u += 0x7fffu + ((u >> 16) & 1u);
    return (unsigned short)(u >> 16);
}
__device__ __forceinline__ float bf2f(unsigned short h) {
    return __uint_as_float((unsigned int)h << 16);
}
__device__ __forceinline__ void split2(float v, unsigned short& hi, unsigned short& lo) {
    hi = f2bf(v);
    lo = f2bf(v - bf2f(hi));
}

// ---------------------------------------------------------------------------
// Prep: weight hi/lo splits, per-(b,t) active-children lists, zero barriers.
// ---------------------------------------------------------------------------
__global__ __launch_bounds__(256) void prep_kernel(
    const int* __restrict__ bfs, const int* __restrict__ children,
    const float* __restrict__ Wix, const float* __restrict__ Wfx, const float* __restrict__ Wux,
    const float* __restrict__ Wih, const float* __restrict__ Wfh, const float* __restrict__ Wuh,
    unsigned short* __restrict__ Wixh, unsigned short* __restrict__ Wixl,
    unsigned short* __restrict__ Wfxh, unsigned short* __restrict__ Wfxl,
    unsigned short* __restrict__ Wuxh, unsigned short* __restrict__ Wuxl,
    unsigned short* __restrict__ Wihh, unsigned short* __restrict__ Wihl,
    unsigned short* __restrict__ Wfhh, unsigned short* __restrict__ Wfhl,
    unsigned short* __restrict__ Wuhh, unsigned short* __restrict__ Wuhl,
    unsigned char* __restrict__ clist, int* __restrict__ ccnt, int* __restrict__ bars)
{
    const int gid = blockIdx.x * 256 + threadIdx.x;
    const int G = gridDim.x * 256;
    for (int i = gid; i < NGRP * SS; i += G) bars[i] = 0;
    for (int i = gid; i < 3 * HH * KP; i += G) {
        int g = i / (HH * KP), rem = i % (HH * KP), r = rem / KP, k = rem % KP;
        const float* src = (g == 0) ? Wix : (g == 1) ? Wfx : Wux;
        unsigned short* dh = (g == 0) ? Wixh : (g == 1) ? Wfxh : Wuxh;
        unsigned short* dl = (g == 0) ? Wixl : (g == 1) ? Wfxl : Wuxl;
        float v = (k < EE) ? src[(size_t)r * EE + k] : 0.0f;
        unsigned short hi, lo; split2(v, hi, lo);
        dh[r * KP + k] = hi; dl[r * KP + k] = lo;
    }
    for (int i = gid; i < 3 * HH * HH; i += G) {
        int g = i / (HH * HH), idx = i % (HH * HH);
        const float* src = (g == 0) ? Wih : (g == 1) ? Wfh : Wuh;
        unsigned short* dh = (g == 0) ? Wihh : (g == 1) ? Wfhh : Wuhh;
        unsigned short* dl = (g == 0) ? Wihl : (g == 1) ? Wfhl : Wuhl;
        unsigned short hi, lo; split2(src[idx], hi, lo);
        dh[idx] = hi; dl[idx] = lo;
    }
    if (gid < BB * SS) {
        const int b = gid >> 6, t = gid & 63;
        unsigned long long w = 0;
        for (int tp = 0; tp < t; ++tp) w |= 1ull << (bfs[b * SS + tp] & 63);
        const int cur = bfs[b * SS + t];
        const int* crow = children + (size_t)(b * SS + cur) * SS;
        unsigned char* lst = clist + (size_t)gid * SS;
        int cnt = 0;
        for (int s = 0; s < SS; ++s)
            if (crow[s] != 0 && ((w >> s) & 1ull)) lst[cnt++] = (unsigned char)s;
        ccnt[gid] = cnt;
    }
}

// ---------------------------------------------------------------------------
// XP precompute, split-bf16 MFMA -> PACKED output XPp[b*64+s][h][g] (g=0:i,1:f,2:u,
// slot3 unused). [8192 x 320] @ [320 x 512] per gate. M=16 tiles, grid (512,3).
// ---------------------------------------------------------------------------
__global__ __launch_bounds__(256) void xp_mfma(
    const int* __restrict__ x, const float* __restrict__ embed,
    const unsigned short* __restrict__ Wixh, const unsigned short* __restrict__ Wixl,
    const unsigned short* __restrict__ Wfxh, const unsigned short* __restrict__ Wfxl,
    const unsigned short* __restrict__ Wuxh, const unsigned short* __restrict__ Wuxl,
    const float* __restrict__ bix, const float* __restrict__ bih,
    const float* __restrict__ bfx, const float* __restrict__ bfh,
    const float* __restrict__ bux, const float* __restrict__ buh,
    float* __restrict__ XPp)
{
    const int mb = blockIdx.x;            // 512 tiles of 16 rows of B*S
    const int g  = blockIdx.y;            // gate
    const unsigned short* __restrict__ Wbh = (g == 0) ? Wixh : (g == 1) ? Wfxh : Wuxh;
    const unsigned short* __restrict__ Wbl = (g == 0) ? Wixl : (g == 1) ? Wfxl : Wuxl;
    const float* __restrict__ b1 = (g == 0) ? bix : (g == 1) ? bfx : bux;
    const float* __restrict__ b2 = (g == 0) ? bih : (g == 1) ? bfh : buh;

    const int row0 = mb * 16;
    __shared__ unsigned short As[2][16 * 328];
    __shared__ int toks[16];

    const int tid = threadIdx.x;
    if (tid < 16) toks[tid] = x[row0 + tid];
    __syncthreads();

    for (int i = tid; i < 16 * 75; i += 256) {
        int r = i / 75, c = i - r * 75;
        const float4 v = *(const float4*)(embed + (size_t)toks[r] * EE + c * 4);
        ushort4 hv, lv;
        split2(v.x, hv.x, lv.x); split2(v.y, hv.y, lv.y);
        split2(v.z, hv.z, lv.z); split2(v.w, hv.w, lv.w);
        *(ushort4*)&As[0][r * 328 + c * 4] = hv;
        *(ushort4*)&As[1][r * 328 + c * 4] = lv;
    }
    for (int i = tid; i < 16 * 20; i += 256) {
        int r = i / 20, k = EE + (i - r * 20);
        As[0][r * 328 + k] = 0; As[1][r * 328 + k] = 0;
    }
    __syncthreads();

    const int lane = tid & 63, wave = tid >> 6;
    const int quad = lane >> 4, col = lane & 15;
    const int wn = wave * 16;

    for (int nt = 0; nt < 8; ++nt) {
        const int gn = nt * 64 + wn + col;        // global output column
        const size_t wrow = (size_t)gn * KP;
        f32x4 accA = {0.f, 0.f, 0.f, 0.f}, accB = {0.f, 0.f, 0.f, 0.f};
        #pragma unroll
        for (int kq = 0; kq < 10; ++kq) {
            const int ka = kq * 32 + quad * 8;
            bf16x8 bh = *(const bf16x8*)(Wbh + wrow + ka);
            bf16x8 bl = *(const bf16x8*)(Wbl + wrow + ka);
            bf16x8 ah = *(const bf16x8*)&As[0][col * 328 + ka];
            bf16x8 al = *(const bf16x8*)&As[1][col * 328 + ka];
            accA = __builtin_amdgcn_mfma_f32_16x16x32_bf16(ah, bh, accA, 0, 0, 0);
            accB = __builtin_amdgcn_mfma_f32_16x16x32_bf16(ah, bl, accB, 0, 0, 0);
            accA = __builtin_amdgcn_mfma_f32_16x16x32_bf16(al, bh, accA, 0, 0, 0);
        }
        const f32x4 acc = accA + accB;
        const float bb = b1[gn] + b2[gn];
        #pragma unroll
        for (int reg = 0; reg < 4; ++reg) {
            const int ml = quad * 4 + reg;
            XPp[((size_t)(row0 + ml) * HH + gn) * 4 + g] = acc[reg] + bb;
        }
    }
}

// ---------------------------------------------------------------------------
// Fused recurrence v3: 256 blocks = 8 groups x 32 h-slice blocks, cooperative.
// Block (g,l) owns chains [16g,16g+16) x h-cols [16l,16l+16) for gates AND the
// matching 48 W-rows for proj -> proj->gates dependency is INTRA-block (L2
// stays warm, only __threadfence_block). The only cross-block item is h(t):
// exchanged via agent-scope relaxed ATOMICS (cache-bypass) + ONE relaxed
// group barrier per step. No agent fences -> no L1/L2 invalidation, ever.
// ---------------------------------------------------------------------------
__global__ __launch_bounds__(256, 1) void fused_steps(
    const int* __restrict__ bfs, const unsigned char* __restrict__ clist,
    const int* __restrict__ ccnt, const float* __restrict__ XPp,
    const unsigned short* __restrict__ Wihh, const unsigned short* __restrict__ Wihl,
    const unsigned short* __restrict__ Wfhh, const unsigned short* __restrict__ Wfhl,
    const unsigned short* __restrict__ Wuhh, const unsigned short* __restrict__ Wuhl,
    float* __restrict__ HWC, float* __restrict__ hf32,
    unsigned int* __restrict__ h_pack, int* __restrict__ bars)
{
    extern __shared__ unsigned short Ws[];      // [plane2][gate3][16][WSROW]
    __shared__ int s_cur[16 * 64];              // bfs per (chain,t)
    __shared__ int s_cnt[16 * 64];              // child count per (chain,t)
    __shared__ unsigned char s_cl[16 * 64];     // child list for current step

    const int g = blockIdx.x & 7;               // group
    const int l = blockIdx.x >> 3;              // h-slice index 0..31
    const int tid = threadIdx.x;
    const int m0 = g * 16;                      // first chain of group
    const int n0 = l * HSL;                     // first h column of block

    const int lane = tid & 63, wave = tid >> 6;
    const int quad = lane >> 4, col = lane & 15;

    // gates task: one (chain, h) per thread
    const int chain = tid >> 4, hl = tid & 15;
    const int b = m0 + chain;
    const int h = n0 + hl;

    // ---- one-time init ----
    {   // weights: 2 planes x 3 gates x 16 rows x 64 16B-chunks = 6144 chunks
        for (int i = tid; i < 6144; i += 256) {
            const int plane = i / 3072, rem = i % 3072;
            const int gt = rem / 1024, rem2 = rem % 1024;
            const int r = rem2 >> 6, c = rem2 & 63;
            const unsigned short* src =
                (plane == 0) ? ((gt == 0) ? Wihh : (gt == 1) ? Wfhh : Wuhh)
                             : ((gt == 0) ? Wihl : (gt == 1) ? Wfhl : Wuhl);
            *(u32x4*)&Ws[((plane * 3 + gt) * 16 + r) * WSROW + c * 8] =
                *(const u32x4*)(src + (size_t)(n0 + r) * HH + c * 8);
        }
        for (int i = tid; i < 16 * 64; i += 256) {
            s_cur[i] = bfs[(m0 + (i >> 6)) * SS + (i & 63)];
            s_cnt[i] = ccnt[(m0 + (i >> 6)) * SS + (i & 63)];
        }
        if (tid < 64) {   // stage child list for t=0
            const int ch = tid >> 2, c = tid & 3;
            ((u32x4*)s_cl)[tid] =
                *(const u32x4*)(clist + ((size_t)(m0 + ch) * SS + 0) * SS + c * 16);
        }
    }
    __syncthreads();

    const size_t browf = (size_t)b * (SS * HH * 4);   // float offset of chain's HWC/XP rows
    float4 xp_c, xp_n;
    {
        const int cur0 = s_cur[(chain << 6) + 0];
        xp_c = *(const float4*)(XPp + browf + (size_t)cur0 * (HH * 4) + h * 4);
    }

    int* gbars = bars + g * SS;

    for (int t = 0; t < SS; ++t) {
        // ================= gates (all threads, 1 task) =================
        const int cur = s_cur[(chain << 6) + t];
        const int cnt = s_cnt[(chain << 6) + t];
        const float xpi = xp_c.x, xpf = xp_c.y, xpu = xp_c.z;
        const float* HWb = HWC + browf + h * 4;       // + child*2048

        float ai = 0.f, af = 0.f, au = 0.f, fc = 0.f;
        int idx = 0;
        while (idx + 4 <= cnt) {                       // 4-deep load pipeline
            const float4 v0 = *(const float4*)(HWb + (size_t)s_cl[(chain << 6) + idx + 0] * 2048);
            const float4 v1 = *(const float4*)(HWb + (size_t)s_cl[(chain << 6) + idx + 1] * 2048);
            const float4 v2 = *(const float4*)(HWb + (size_t)s_cl[(chain << 6) + idx + 2] * 2048);
            const float4 v3 = *(const float4*)(HWb + (size_t)s_cl[(chain << 6) + idx + 3] * 2048);
            ai += v0.x + v1.x + v2.x + v3.x;
            af += v0.y + v1.y + v2.y + v3.y;
            au += v0.z + v1.z + v2.z + v3.z;
            fc += fast_sigmoid(v0.y + xpf) * v0.w + fast_sigmoid(v1.y + xpf) * v1.w
                + fast_sigmoid(v2.y + xpf) * v2.w + fast_sigmoid(v3.y + xpf) * v3.w;
            idx += 4;
        }
        while (idx < cnt) {
            const float4 v = *(const float4*)(HWb + (size_t)s_cl[(chain << 6) + idx] * 2048);
            ai += v.x; af += v.y; au += v.z;
            fc += fast_sigmoid(v.y + xpf) * v.w;
            ++idx;
        }

        const float ig = fast_sigmoid(xpi + ai);
        const float og = fast_sigmoid(xpf + af);      // o shares fx/fh per source
        const float ug = fast_tanh(xpu + au);
        const float c  = ig * ug + fc;
        const float hv = og * fast_tanh(c);

        HWC[browf + (size_t)cur * 2048 + h * 4 + 3] = c;   // C slot (block-local)
        if (t == SS - 1) {
            hf32[(size_t)b * HH + h] = hv;
            break;
        }
        {   // publish h via cache-bypass store (agent scope)
            unsigned short hh, hlo; split2(hv, hh, hlo);
            const unsigned int pk = ((unsigned int)hh << 16) | hlo;
            __hip_atomic_store(&h_pack[(size_t)b * HH + h], pk,
                               __ATOMIC_RELAXED, __HIP_MEMORY_SCOPE_AGENT);
        }
        // prefetch next step's XP (latency hidden behind barrier)
        {
            const int curn = s_cur[(chain << 6) + t + 1];
            xp_n = *(const float4*)(XPp + browf + (size_t)curn * (HH * 4) + h * 4);
        }

        // ============ one relaxed group barrier (h visibility) ============
        __asm__ volatile("s_waitcnt vmcnt(0)" ::: "memory");  // drain h stores
        __syncthreads();
        if (tid == 0) {
            int* cntp = gbars + t;
            __hip_atomic_fetch_add(cntp, 1, __ATOMIC_RELAXED, __HIP_MEMORY_SCOPE_AGENT);
            while (__hip_atomic_load(cntp, __ATOMIC_RELAXED, __HIP_MEMORY_SCOPE_AGENT) < BPG)
                __builtin_amdgcn_s_sleep(1);
        }
        __syncthreads();

        // ================= proj (waves 0-2) / service (wave 3) =============
        if (wave < 3) {
            f32x4 accA = {0.f, 0.f, 0.f, 0.f}, accB = {0.f, 0.f, 0.f, 0.f};
            const size_t hbase = (size_t)(m0 + col) * HH;   // chain = col
            #pragma unroll
            for (int kq = 0; kq < 16; ++kq) {
                const int ka = kq * 32 + quad * 8;
                unsigned long long q0 = __hip_atomic_load(
                    (unsigned long long*)(h_pack + hbase + ka + 0), __ATOMIC_RELAXED, __HIP_MEMORY_SCOPE_AGENT);
                unsigned long long q1 = __hip_atomic_load(
                    (unsigned long long*)(h_pack + hbase + ka + 2), __ATOMIC_RELAXED, __HIP_MEMORY_SCOPE_AGENT);
                unsigned long long q2 = __hip_atomic_load(
                    (unsigned long long*)(h_pack + hbase + ka + 4), __ATOMIC_RELAXED, __HIP_MEMORY_SCOPE_AGENT);
                unsigned long long q3 = __hip_atomic_load(
                    (unsigned long long*)(h_pack + hbase + ka + 6), __ATOMIC_RELAXED, __HIP_MEMORY_SCOPE_AGENT);
                union { unsigned int u[4]; bf16x8 v; } ah, al;
                {
                    unsigned int a, bq;
                    a = (unsigned int)q0; bq = (unsigned int)(q0 >> 32);
                    ah.u[0] = (a >> 16) | (bq & 0xffff0000u); al.u[0] = (a & 0xffffu) | (bq << 16);
                    a = (unsigned int)q1; bq = (unsigned int)(q1 >> 32);
                    ah.u[1] = (a >> 16) | (bq & 0xffff0000u); al.u[1] = (a & 0xffffu) | (bq << 16);
                    a = (unsigned int)q2; bq = (unsigned int)(q2 >> 32);
                    ah.u[2] = (a >> 16) | (bq & 0xffff0000u); al.u[2] = (a & 0xffffu) | (bq << 16);
                    a = (unsigned int)q3; bq = (unsigned int)(q3 >> 32);
                    ah.u[3] = (a >> 16) | (bq & 0xffff0000u); al.u[3] = (a & 0xffffu) | (bq << 16);
                }
                bf16x8 bh = *(const bf16x8*)&Ws[((0 * 3 + wave) * 16 + col) * WSROW + ka];
                bf16x8 bl = *(const bf16x8*)&Ws[((1 * 3 + wave) * 16 + col) * WSROW + ka];
                accA = __builtin_amdgcn_mfma_f32_16x16x32_bf16(ah.v, bh, accA, 0, 0, 0);
                accB = __builtin_amdgcn_mfma_f32_16x16x32_bf16(ah.v, bl, accB, 0, 0, 0);
                accA = __builtin_amdgcn_mfma_f32_16x16x32_bf16(al.v, bh, accA, 0, 0, 0);
            }
            const f32x4 acc = accA + accB;
            // scatter: D col=lane&15 -> W-row j (h col n0+j); row quad*4+reg -> chain
            #pragma unroll
            for (int reg = 0; reg < 4; ++reg) {
                const int m = quad * 4 + reg;
                const int curm = s_cur[(m << 6) + t];
                HWC[(size_t)(m0 + m) * (SS * HH * 4) + (size_t)curm * 2048
                    + (n0 + col) * 4 + wave] = acc[reg];
            }
        } else {
            // stage child lists for step t+1
            if (lane < 64) {
                const int ch = lane >> 2, cc = lane & 3;
                ((u32x4*)s_cl)[lane] =
                    *(const u32x4*)(clist + ((size_t)(m0 + ch) * SS + (t + 1)) * SS + cc * 16);
            }
        }
        __threadfence_block();      // proj scatter -> next gates (same block)
        __syncthreads();
        xp_c = xp_n;
    }
}

// ---------------------------------------------------------------------------
// Final projection: out[b,l] = hf32[b,:] . Wout[l,:] + bout[l]
// ---------------------------------------------------------------------------
__global__ __launch_bounds__(64) void out_kernel(
    const float* __restrict__ hcur,
    const float* __restrict__ Wout, const float* __restrict__ bout,
    float* __restrict__ out)
{
    const int b = blockIdx.x;
    const int lane = threadIdx.x;
    float acc[LL];
    #pragma unroll
    for (int l = 0; l < LL; ++l) acc[l] = 0.0f;
    for (int h = lane; h < HH; h += 64) {
        const float hv = hcur[(size_t)b * HH + h];
        #pragma unroll
        for (int l = 0; l < LL; ++l) acc[l] += hv * Wout[l * HH + h];
    }
    #pragma unroll
    for (int off = 32; off > 0; off >>= 1) {
        #pragma unroll
        for (int l = 0; l < LL; ++l) acc[l] += __shfl_down(acc[l], off);
    }
    if (lane == 0) {
        #pragma unroll
        for (int l = 0; l < LL; ++l) out[b * LL + l] = acc[l] + bout[l];
    }
}

extern "C" void kernel_launch(void* const* d_in, const int* in_sizes, int n_in,
                              void* d_out, int out_size, void* d_ws, size_t ws_size,
                              hipStream_t stream)
{
    (void)in_sizes; (void)n_in; (void)out_size; (void)ws_size;
    const int*   x        = (const int*)d_in[0];
    const int*   bfs      = (const int*)d_in[1];
    const int*   children = (const int*)d_in[2];
    const float* embed    = (const float*)d_in[3];
    const float* Wix = (const float*)d_in[4];
    const float* bix = (const float*)d_in[5];
    const float* Wih = (const float*)d_in[6];
    const float* bih = (const float*)d_in[7];
    const float* Wfx = (const float*)d_in[8];
    const float* bfx = (const float*)d_in[9];
    const float* Wfh = (const float*)d_in[10];
    const float* bfh = (const float*)d_in[11];
    const float* Wux = (const float*)d_in[12];
    const float* bux = (const float*)d_in[13];
    const float* Wuh = (const float*)d_in[14];
    const float* buh = (const float*)d_in[15];
    const float* Wout = (const float*)d_in[16];
    const float* bout = (const float*)d_in[17];
    float* out = (float*)d_out;

    // Workspace (~141 MB)
    char* p = (char*)d_ws;
    float* XPp = (float*)p;            p += (size_t)BSH * 4 * 4;   // packed i,f,u,pad
    float* HWC = (float*)p;            p += (size_t)BSH * 4 * 4;   // packed HWi,HWf,HWu,C
    float* hf32 = (float*)p;           p += (size_t)BB * HH * 4;
    unsigned int* h_pack = (unsigned int*)p;   p += (size_t)BB * HH * 4;
    unsigned short* Wixh = (unsigned short*)p; p += (size_t)HH * KP * 2;
    unsigned short* Wixl = (unsigned short*)p; p += (size_t)HH * KP * 2;
    unsigned short* Wfxh = (unsigned short*)p; p += (size_t)HH * KP * 2;
    unsigned short* Wfxl = (unsigned short*)p; p += (size_t)HH * KP * 2;
    unsigned short* Wuxh = (unsigned short*)p; p += (size_t)HH * KP * 2;
    unsigned short* Wuxl = (unsigned short*)p; p += (size_t)HH * KP * 2;
    unsigned short* Wihh = (unsigned short*)p; p += (size_t)HH * HH * 2;
    unsigned short* Wihl = (unsigned short*)p; p += (size_t)HH * HH * 2;
    unsigned short* Wfhh = (unsigned short*)p; p += (size_t)HH * HH * 2;
    unsigned short* Wfhl = (unsigned short*)p; p += (size_t)HH * HH * 2;
    unsigned short* Wuhh = (unsigned short*)p; p += (size_t)HH * HH * 2;
    unsigned short* Wuhl = (unsigned short*)p; p += (size_t)HH * HH * 2;
    unsigned char* clist = (unsigned char*)p;  p += (size_t)BB * SS * SS;
    int* ccnt = (int*)p;               p += (size_t)BB * SS * 4;
    int* bars = (int*)p;               p += (size_t)NGRP * SS * 4;

    (void)hipFuncSetAttribute((const void*)fused_steps,
                              hipFuncAttributeMaxDynamicSharedMemorySize,
                              WS_BYTES);

    prep_kernel<<<dim3(256), 256, 0, stream>>>(
        bfs, children, Wix, Wfx, Wux, Wih, Wfh, Wuh,
        Wixh, Wixl, Wfxh, Wfxl, Wuxh, Wuxl,
        Wihh, Wihl, Wfhh, Wfhl, Wuhh, Wuhl, clist, ccnt, bars);

    xp_mfma<<<dim3(512, 3), 256, 0, stream>>>(
        x, embed, Wixh, Wixl, Wfxh, Wfxl, Wuxh, Wuxl,
        bix, bih, bfx, bfh, bux, buh, XPp);

    {
        void* args[] = {
            (void*)&bfs, (void*)&clist, (void*)&ccnt, (void*)&XPp,
            (void*)&Wihh, (void*)&Wihl, (void*)&Wfhh, (void*)&Wfhl,
            (void*)&Wuhh, (void*)&Wuhl,
            (void*)&HWC, (void*)&hf32, (void*)&h_pack, (void*)&bars
        };
        hipLaunchCooperativeKernel((void*)fused_steps, dim3(NGRP * BPG), dim3(256),
                                   args, WS_BYTES, stream);
    }

    out_kernel<<<dim3(BB), 64, 0, stream>>>(hf32, Wout, bout, out);
}